// Round 11
// baseline (59.688 us; speedup 1.0000x reference)
//
#include <hip/hip_runtime.h>
#include <hip/hip_bf16.h>
#include <math.h>

#define CHN  12
#define H    256
#define W    256
#define HID  128
#define OUTC 9
#define PSTR 56   // perc row stride in shorts: 48 data + 8 const-pad (112 B -> 7-coprime slot rotation)
#define YSTR 72   // y1 row stride in shorts: 64 data + 8 pad (144 B -> +1 slot rotation/row)

typedef __attribute__((ext_vector_type(4))) float    f32x4;
typedef __attribute__((ext_vector_type(8))) short    s16x8;
typedef __attribute__((ext_vector_type(4))) unsigned u32x4;
typedef __attribute__((ext_vector_type(8))) __bf16   bf16x8;

#define MFMA16x16x32(a, b, c) \
    __builtin_amdgcn_mfma_f32_16x16x32_bf16(__builtin_bit_cast(bf16x8, (a)), \
                                            __builtin_bit_cast(bf16x8, (b)), (c), 0, 0, 0)

static __device__ __forceinline__ unsigned short bfbits(float f) {
    __hip_bfloat16 h = __float2bfloat16(f);   // RNE (prep kernel only)
    return __builtin_bit_cast(unsigned short, h);
}
static __device__ __forceinline__ float bits2f(unsigned short u) {
    __hip_bfloat16 h = __builtin_bit_cast(__hip_bfloat16, u);
    return __bfloat162float(h);
}
// round-to-nearest-away bf16 in the bit domain: high 16 bits of (u + 0x8000)
static __device__ __forceinline__ unsigned rna(float f) {
    return __builtin_bit_cast(unsigned, f) + 0x8000u;
}
// pack two rna()'d words into bf16x2 (even -> low half, odd -> high half): 1 v_perm_b32
static __device__ __forceinline__ unsigned pack2(unsigned uodd, unsigned ueven) {
    return __builtin_amdgcn_perm(uodd, ueven, 0x07060302u);
}
static __device__ __forceinline__ float fast_sqrtf(float x) {
    float r;
    asm("v_sqrt_f32 %0, %1" : "=v"(r) : "v"(x));
    return r;
}

// ---------------- prologue: bake weight fragments into d_ws ----------------
// ws layout:
//   [0)      a1 : ushort [16][64][8]  (mf = m*2+f; f=0 -> k 0..31, f=1 -> k 32..63)
//            k slots: 0..35 = w1 cols, 36..47 = w1 col 2(s-36)+1 (pairs with lap
//            residual-lo), 48 = w1b (pairs with constant 1.0 in perc pad), 49..63 = 0
//   [16384)  a2 : ushort [4][64][8]   bf16 w2 (leaky applied on VALU before pack)
__global__ void prep_weights(const float* __restrict__ w1w, const float* __restrict__ w1b,
                             const float* __restrict__ w2w, unsigned short* __restrict__ wsbuf)
{
    const int t = threadIdx.x;      // 256 threads, one block
    const int l = t & 63;
    const int grp = t >> 6;
    const int row = l & 15;
    const int g4 = l >> 4;
    unsigned short* wsa1 = wsbuf;
    unsigned short* wsa2 = wsbuf + 16 * 64 * 8;

    for (int mf = grp; mf < 16; mf += 4) {
        int m = mf >> 1, f = mf & 1;
        int hid = m * 16 + row;
        for (int j = 0; j < 8; ++j) {
            int s = f * 32 + g4 * 8 + j;
            unsigned short v = 0;
            if (s < 36)       v = bfbits(w1w[hid * 36 + s]);
            else if (s < 48)  v = bfbits(w1w[hid * 36 + 2 * (s - 36) + 1]);  // lap residual partner
            else if (s == 48) v = bfbits(w1b[hid]);                          // bias slot
            wsa1[(mf * 64 + l) * 8 + j] = v;
        }
    }
    {
        int kb = grp;
        for (int j = 0; j < 8; ++j) {
            float wv = (row < OUTC) ? w2w[row * HID + kb * 32 + g4 * 8 + j] : 0.f;
            wsa2[(kb * 64 + l) * 8 + j] = bfbits(wv);
        }
    }
}

// ---------------- main fused kernel: ONE WAVE PER BLOCK (64 px quarter-row) ----------------
// Each wave is fully independent (direct 3x3 global-stencil, wave-private LDS,
// no __syncthreads). 9.5 KB LDS/block -> ~16 blocks/CU; single a2 set keeps
// total regs <= 128 -> 4 waves/SIMD under __launch_bounds__(64,4).
__global__ __launch_bounds__(64, 4) void nca_main(
    const float* __restrict__ x, const float* __restrict__ rnd,
    const unsigned short* __restrict__ wsbuf, float* __restrict__ out)
{
    __shared__ unsigned short perc_lds[64][PSTR];   // 7,168 B
    __shared__ unsigned short y1h[16][YSTR];        // 2,304 B -> total 9,472 B

    const int t = threadIdx.x;   // lane 0..63
    // XCD-chunked bijective swizzle: 16384 blocks = 8 XCDs x 2048 contiguous
    const int orig = ((blockIdx.x & 7) << 11) | (blockIdx.x >> 3);
    const int q   = orig & 3;           // quarter-row
    const int row = orig >> 2;          // 0..4095
    const int h = row & (H - 1);
    const int b = row >> 8;
    const int col = q * 64 + t;
    const int hm = (h + H - 1) & (H - 1);
    const int hp = (h + 1) & (H - 1);
    const float* xb = x + (size_t)b * CHN * H * W;

    const int wm = (col + W - 1) & (W - 1);
    const int wp = (col + 1) & (W - 1);
    const float maskraw = rnd[((size_t)b * H + h) * W + col];   // issue early

    // ---- phase AB: direct 3x3 stencil per channel, no barriers ----
    float perc[36];
    float scale_reg = 0.f;
    #pragma unroll
    for (int c = 0; c < CHN; ++c) {
        const float* rm = xb + (size_t)c * H * W + (size_t)hm * W;
        const float* rc = xb + (size_t)c * H * W + (size_t)h  * W;
        const float* rp = xb + (size_t)c * H * W + (size_t)hp * W;
        float v00 = rm[wm], v01 = rm[col], v02 = rm[wp];
        float v10 = rc[wm], v11 = rc[col], v12 = rc[wp];
        float v20 = rp[wm], v21 = rp[col], v22 = rp[wp];

        float csm = fmaf(2.f, v10, v00) + v20;     // col sums (vertical [1,2,1])
        float csc = fmaf(2.f, v11, v01) + v21;
        float csp = fmaf(2.f, v12, v02) + v22;
        float gx  = csp - csm;                                        // SOBEL_X
        float gy  = fmaf(2.f, v21 - v01, (v20 - v00) + (v22 - v02));  // SOBEL_X^T
        float lap = fmaf(2.f, csc, csm + csp) - 16.f * v11;           // LAP

        perc[2 * c]     = v11;
        perc[2 * c + 1] = lap;
        perc[24 + c]    = fast_sqrtf(fmaf(gx, gx, gy * gy) + 1e-8f);

        if (c == 3) {   // 3x3 max-pool of channel 3, CLAMPED edges
            float cmm = v10, cmc = v11, cmp = v12;
            if (h > 0)     { cmm = fmaxf(cmm, v00); cmc = fmaxf(cmc, v01); cmp = fmaxf(cmp, v02); }
            if (h < H - 1) { cmm = fmaxf(cmm, v20); cmc = fmaxf(cmc, v21); cmp = fmaxf(cmp, v22); }
            float pool = cmc;
            if (col > 0)     pool = fmaxf(pool, cmm);
            if (col < W - 1) pool = fmaxf(pool, cmp);
            scale_reg = (pool > 0.1f && maskraw >= 0.5f) ? 1.f : 0.f;  // floor(r+0.5) == (r>=0.5)
        }
        if (c >= CHN - 3) {   // gene channels: exact passthrough of center
            out[((size_t)b * CHN + c) * H * W + (size_t)h * W + col] = v11;
        }
    }

    // ---- phase C: bit-domain bf16 pack (RNA + v_perm), 6 data + 1 const granule ----
    {
        unsigned u[48];
        #pragma unroll
        for (int s = 0; s < 36; ++s) u[s] = rna(perc[s]);
        #pragma unroll
        for (int k = 0; k < 12; ++k) {
            float hif = __builtin_bit_cast(float, u[2 * k + 1] & 0xFFFF0000u);
            u[36 + k] = rna(perc[2 * k + 1] - hif);
        }
        unsigned short* prow = &perc_lds[t][0];
        #pragma unroll
        for (int g = 0; g < 6; ++g) {
            u32x4 v;
            #pragma unroll
            for (int j = 0; j < 4; ++j)
                v[j] = pack2(u[8 * g + 2 * j + 1], u[8 * g + 2 * j]);
            *(u32x4*)&prow[g * 8] = v;
        }
        // const pad granule, slots 48..55: {1.0(bias partner), 0 x 7}
        u32x4 vpad;
        vpad[0] = 0x3F80u; vpad[1] = 0u; vpad[2] = 0u; vpad[3] = 0u;
        *(u32x4*)&prow[48] = vpad;
    }
    // all perc rows written by this same wave -> no barrier.

    // ---- phase D: load prepped weight fragments (coalesced 16B/lane, L2-hot) ----
    const int p16 = t & 15;
    const int g4 = t >> 4;
    const s16x8* A1 = (const s16x8*)wsbuf;   // [16][64]
    const s16x8* A2 = A1 + 16 * 64;

    s16x8 a1f[16];
    #pragma unroll
    for (int mf = 0; mf < 16; ++mf) a1f[mf] = A1[mf * 64 + t];
    s16x8 a2[4];
    #pragma unroll
    for (int kb = 0; kb < 4; ++kb) a2[kb] = A2[kb * 64 + t];

    const f32x4 fzero = {0.f, 0.f, 0.f, 0.f};

    // ---- phase E: per-16-pixel tile: GEMM1 -> leaky+pack -> GEMM2 -> store ----
    #pragma unroll 1
    for (int pt = 0; pt < 4; ++pt) {
        const int p = pt * 16 + p16;              // pixel index within wave
        const unsigned short* prow = &perc_lds[p][0];
        s16x8 blo = *(const s16x8*)&prow[g4 * 8];               // k 0..31
        s16x8 bhi;
        #pragma unroll
        for (int j = 0; j < 8; ++j) bhi[j] = 0;                 // k 48..63 zeros (g4==3)
        if (g4 < 3) bhi = *(const s16x8*)&prow[(4 + g4) * 8];   // k 32..55 incl. const pad

        unsigned short* ybase = &y1h[p16][0];
        f32x4 acc2 = fzero;

        #pragma unroll
        for (int hh = 0; hh < 2; ++hh) {
            f32x4 acc[4];
            #pragma unroll
            for (int m2 = 0; m2 < 4; ++m2) {
                acc[m2] = MFMA16x16x32(a1f[(hh * 4 + m2) * 2],     blo, fzero);
                acc[m2] = MFMA16x16x32(a1f[(hh * 4 + m2) * 2 + 1], bhi, acc[m2]);
            }
            // leaky relu (exact: max(v, 0.01v)) + RNA/perm pack -> b64 write
            #pragma unroll
            for (int m2 = 0; m2 < 4; ++m2) {
                float w0 = fmaxf(acc[m2][0], 0.01f * acc[m2][0]);
                float w1 = fmaxf(acc[m2][1], 0.01f * acc[m2][1]);
                float w2 = fmaxf(acc[m2][2], 0.01f * acc[m2][2]);
                float w3 = fmaxf(acc[m2][3], 0.01f * acc[m2][3]);
                unsigned lo = pack2(rna(w1), rna(w0));
                unsigned hi = pack2(rna(w3), rna(w2));
                *(uint2*)(ybase + (2 * m2 + (g4 >> 1)) * 8 + (g4 & 1) * 4) = make_uint2(lo, hi);
            }
            #pragma unroll
            for (int kb2 = 0; kb2 < 2; ++kb2) {
                u32x4 b2 = *(const u32x4*)(ybase + (kb2 * 4 + g4) * 8);
                acc2 = MFMA16x16x32(a2[hh * 2 + kb2], b2, acc2);
            }
        }

        const float sc = __shfl(scale_reg, p, 64);
        const size_t pixbase = (size_t)b * CHN * H * W + (size_t)h * W + (q * 64 + p);
        #pragma unroll
        for (int r = 0; r < 4; ++r) {
            int o = g4 * 4 + r;
            if (o < OUTC) {
                // x center (bf16-rounded) is already in blo: slot 2*o -> element 2r
                float xhi = bits2f((unsigned short)blo[2 * r]);
                out[pixbase + (size_t)o * H * W] = fmaf(acc2[r], sc, xhi);
            }
        }
    }
}

extern "C" void kernel_launch(void* const* d_in, const int* in_sizes, int n_in,
                              void* d_out, int out_size, void* d_ws, size_t ws_size,
                              hipStream_t stream) {
    const float* x   = (const float*)d_in[0];
    const float* rnd = (const float*)d_in[1];
    const float* w1w = (const float*)d_in[2];
    const float* w1b = (const float*)d_in[3];
    const float* w2w = (const float*)d_in[4];
    float* out = (float*)d_out;
    unsigned short* ws = (unsigned short*)d_ws;

    prep_weights<<<dim3(1), dim3(256), 0, stream>>>(w1w, w1b, w2w, ws);
    nca_main<<<dim3(16 * 256 * 4), dim3(64), 0, stream>>>(x, rnd, ws, out);
}

// Round 13
// 52.353 us; speedup vs baseline: 1.1401x; 1.1401x over previous
//
#include <hip/hip_runtime.h>
#include <hip/hip_bf16.h>
#include <math.h>

#define CHN  12
#define H    256
#define W    256
#define HID  128
#define OUTC 9
#define PSTR 56   // perc row stride in shorts: 48 data + 8 const-pad (112 B -> 7-coprime slot rotation)

typedef __attribute__((ext_vector_type(4))) float    f32x4;
typedef __attribute__((ext_vector_type(8))) short    s16x8;
typedef __attribute__((ext_vector_type(4))) unsigned u32x4;
typedef __attribute__((ext_vector_type(8))) __bf16   bf16x8;

#define MFMA16x16x32(a, b, c) \
    __builtin_amdgcn_mfma_f32_16x16x32_bf16(__builtin_bit_cast(bf16x8, (a)), \
                                            __builtin_bit_cast(bf16x8, (b)), (c), 0, 0, 0)

static __device__ __forceinline__ unsigned short bfbits(float f) {
    __hip_bfloat16 h = __float2bfloat16(f);   // RNE (prep kernel only)
    return __builtin_bit_cast(unsigned short, h);
}
static __device__ __forceinline__ float bits2f(unsigned short u) {
    __hip_bfloat16 h = __builtin_bit_cast(__hip_bfloat16, u);
    return __bfloat162float(h);
}
// round-to-nearest-away bf16 in the bit domain: high 16 bits of (u + 0x8000)
static __device__ __forceinline__ unsigned rna(float f) {
    return __builtin_bit_cast(unsigned, f) + 0x8000u;
}
// pack two rna()'d words into bf16x2 (even -> low half, odd -> high half): 1 v_perm_b32
static __device__ __forceinline__ unsigned pack2(unsigned uodd, unsigned ueven) {
    return __builtin_amdgcn_perm(uodd, ueven, 0x07060302u);
}
static __device__ __forceinline__ float fast_sqrtf(float x) {
    float r;
    asm("v_sqrt_f32 %0, %1" : "=v"(r) : "v"(x));
    return r;
}

// ---------------- prologue: bake weight fragments into d_ws ----------------
// hid-row PERMUTATION (makes GEMM1 C-layout == GEMM2 B-layout per lane, no shuffle):
//   GEMM1 row-slot (m = hh*4+m2, rho = A-row 0..15)  -> physical hid = hh*64 + (rho>>2)*16 + m2*4 + (rho&3)
//   GEMM2 k-slot  (kb = hh*2+kb2, g4, j)             -> physical hid = hh*64 + g4*16 + kb2*8 + j
//   => lane (p16,g4) GEMM1 outputs {hh*64+g4*16+m2*4+r} == its GEMM2 needs {hh*64+g4*16+kb2*8+j}
// ws layout:
//   [0)      a1  : ushort [16][64][8]  (mf = m*2+f; f=0 -> k 0..31, f=1 -> k 32..63)
//            k slots: 0..35 = w1 cols, 36..47 = w1 col 2(s-36)+1 (pairs with lap
//            residual-lo), 48 = w1b (pairs with constant 1.0 in perc pad), 49..63 = 0
//   [16384)  a2p : ushort [4][64][8]   bf16(0.505*w2)  -- pairs with v
//   [20480)  a2n : ushort [4][64][8]   bf16(0.495*w2)  -- pairs with |v|
//            (leaky(v) = 0.505 v + 0.495 |v|; v>0 -> v, v<0 -> 0.01 v)
__global__ void prep_weights(const float* __restrict__ w1w, const float* __restrict__ w1b,
                             const float* __restrict__ w2w, unsigned short* __restrict__ wsbuf)
{
    const int t = threadIdx.x;      // 256 threads, one block
    const int l = t & 63;
    const int grp = t >> 6;
    const int row = l & 15;         // rho (a1) / output channel (a2)
    const int g4 = l >> 4;
    unsigned short* wsa1  = wsbuf;
    unsigned short* wsa2p = wsbuf + 16 * 64 * 8;
    unsigned short* wsa2n = wsa2p + 4 * 64 * 8;

    for (int mf = grp; mf < 16; mf += 4) {
        int m = mf >> 1, f = mf & 1;
        int hh = m >> 2, m2 = m & 3;
        int hid = hh * 64 + (row >> 2) * 16 + m2 * 4 + (row & 3);   // permuted physical hid
        for (int j = 0; j < 8; ++j) {
            int s = f * 32 + g4 * 8 + j;
            unsigned short v = 0;
            if (s < 36)       v = bfbits(w1w[hid * 36 + s]);
            else if (s < 48)  v = bfbits(w1w[hid * 36 + 2 * (s - 36) + 1]);  // lap residual partner
            else if (s == 48) v = bfbits(w1b[hid]);                          // bias slot
            wsa1[(mf * 64 + l) * 8 + j] = v;
        }
    }
    {
        int kb = grp;
        int hh = kb >> 1, kb2 = kb & 1;
        for (int j = 0; j < 8; ++j) {
            int hid = hh * 64 + g4 * 16 + kb2 * 8 + j;              // same permutation
            float wv = (row < OUTC) ? w2w[row * HID + hid] : 0.f;
            wsa2p[(kb * 64 + l) * 8 + j] = bfbits(0.505f * wv);
            wsa2n[(kb * 64 + l) * 8 + j] = bfbits(0.495f * wv);
        }
    }
}

// ---------------- main fused kernel: one block per (batch,row) ----------------
__global__ __launch_bounds__(256, 3) void nca_main(
    const float* __restrict__ x, const float* __restrict__ rnd,
    const unsigned short* __restrict__ wsbuf, float* __restrict__ out)
{
    union SMem {
        struct { float2 csdd[CHN][W]; float prrow[W]; } s;  // live A..B only
        unsigned short perc[W][PSTR];                       // live C..E (28,672 B)
    };
    __shared__ SMem sm;   // total LDS = 28,672 B (y1 path is now pure registers)

    const int t = threadIdx.x;
    // XCD-aware bijective swizzle: XCD k gets contiguous orig ids -> halo reuse in its L2
    const int orig = ((blockIdx.x & 7) << 9) | (blockIdx.x >> 3);
    const int h = orig & (H - 1);
    const int b = orig >> 8;
    const int hm = (h + H - 1) & (H - 1);
    const int hp = (h + 1) & (H - 1);
    const float* xb = x + (size_t)b * CHN * H * W;

    // ---- phase A: vertical separable pass (registers), write col sums/diffs ----
    float xc[CHN], csr[CHN], ddr[CHN];
    const float maskraw = rnd[((size_t)b * H + h) * W + t];   // issue early
    #pragma unroll
    for (int c = 0; c < CHN; ++c) {
        const float* xp = xb + (size_t)c * H * W;
        float v0 = xp[hm * W + t];
        float v1 = xp[h  * W + t];
        float v2 = xp[hp * W + t];
        xc[c] = v1;
        float cs = fmaf(2.f, v1, v0) + v2;
        float dd = v2 - v0;
        csr[c] = cs; ddr[c] = dd;
        sm.s.csdd[c][t] = make_float2(cs, dd);
        if (c == 3) {   // pool col-max, CLAMPED h-edges
            float cm = v1;
            if (h > 0)     cm = fmaxf(cm, v0);
            if (h < H - 1) cm = fmaxf(cm, v2);
            sm.s.prrow[t] = cm;
        }
    }
    __syncthreads();

    // ---- phase B: horizontal pass -> perc[36], pool/life/mask ----
    const int wm = (t + W - 1) & (W - 1);
    const int wp = (t + 1) & (W - 1);
    float perc[36];
    #pragma unroll
    for (int c = 0; c < CHN; ++c) {
        float2 vm = sm.s.csdd[c][wm];
        float2 vp = sm.s.csdd[c][wp];
        float gx  = vp.x - vm.x;                            // SOBEL_X
        float gy  = fmaf(2.f, ddr[c], vm.y) + vp.y;         // SOBEL_X^T
        float lap = fmaf(2.f, csr[c], vm.x + vp.x) - 16.f * xc[c];
        perc[2 * c]     = xc[c];
        perc[2 * c + 1] = lap;
        perc[24 + c]    = fast_sqrtf(fmaf(gx, gx, gy * gy) + 1e-8f);
    }
    float scale_reg;
    {
        float pool = sm.s.prrow[t];
        if (t > 0)     pool = fmaxf(pool, sm.s.prrow[wm]);   // clamped w-edges
        if (t < W - 1) pool = fmaxf(pool, sm.s.prrow[wp]);
        scale_reg = (pool > 0.1f && maskraw >= 0.5f) ? 1.f : 0.f;  // floor(r+0.5) == (r>=0.5)
    }
    // ---- gene channels passthrough: store EARLY, frees regs through D/E ----
    {
        size_t gidx = ((size_t)b * CHN + 9) * H * W + (size_t)h * W + t;
        out[gidx]                     = xc[9];
        out[gidx + (size_t)H * W]     = xc[10];
        out[gidx + 2 * (size_t)H * W] = xc[11];
    }
    __syncthreads();   // everyone done reading sm.s before aliasing it with perc

    // ---- phase C: bit-domain bf16 pack (RNA + v_perm), 6 data + 1 const granule ----
    {
        unsigned u[48];
        #pragma unroll
        for (int s = 0; s < 36; ++s) u[s] = rna(perc[s]);
        #pragma unroll
        for (int k = 0; k < 12; ++k) {
            float hif = __builtin_bit_cast(float, u[2 * k + 1] & 0xFFFF0000u);
            u[36 + k] = rna(perc[2 * k + 1] - hif);
        }
        unsigned short* prow = &sm.perc[t][0];
        #pragma unroll
        for (int g = 0; g < 6; ++g) {
            u32x4 v;
            #pragma unroll
            for (int j = 0; j < 4; ++j)
                v[j] = pack2(u[8 * g + 2 * j + 1], u[8 * g + 2 * j]);
            *(u32x4*)&prow[g * 8] = v;
        }
        // const pad granule, slots 48..55: {1.0(bias partner), 0 x 7}
        u32x4 vpad;
        vpad[0] = 0x3F80u; vpad[1] = 0u; vpad[2] = 0u; vpad[3] = 0u;
        *(u32x4*)&prow[48] = vpad;
    }
    // perc rows for this wave's 64 pixels were written by this same wave -> no barrier.

    // ---- phase D: load prepped weight fragments (coalesced 16B/lane, L2-hot) ----
    const int l = t & 63;
    const int wv = t >> 6;
    const int p16 = l & 15;
    const int g4 = l >> 4;
    const s16x8* A1  = (const s16x8*)wsbuf;   // [16][64]
    const s16x8* A2P = A1 + 16 * 64;
    const s16x8* A2N = A2P + 4 * 64;

    s16x8 a1f[16];
    #pragma unroll
    for (int mf = 0; mf < 16; ++mf) a1f[mf] = A1[mf * 64 + l];
    s16x8 a2p[4], a2n[4];
    #pragma unroll
    for (int kb = 0; kb < 4; ++kb) { a2p[kb] = A2P[kb * 64 + l]; a2n[kb] = A2N[kb * 64 + l]; }

    const f32x4 fzero = {0.f, 0.f, 0.f, 0.f};

    // ---- phase E: per-16-pixel tile: GEMM1 -> lane-local repack -> GEMM2 -> store ----
    // hid permutation in the baked weights makes each lane's GEMM1 outputs exactly
    // its own GEMM2 B-fragment: bv[d] = pair(y1[g4*16+kb2*8+2d], +1) = acc[2kb2+(d>>1)][2(d&1)..+1]
    #pragma unroll 2
    for (int pt = 0; pt < 4; ++pt) {
        const int p = wv * 64 + pt * 16 + p16;
        const unsigned short* prow = &sm.perc[p][0];
        s16x8 blo = *(const s16x8*)&prow[g4 * 8];               // k 0..31
        s16x8 bhi;
        #pragma unroll
        for (int j = 0; j < 8; ++j) bhi[j] = 0;                 // k 48..63 zeros (g4==3)
        if (g4 < 3) bhi = *(const s16x8*)&prow[(4 + g4) * 8];   // k 32..55 incl. const pad

        f32x4 acc2 = fzero;

        #pragma unroll
        for (int hh = 0; hh < 2; ++hh) {
            f32x4 acc[4];
            #pragma unroll
            for (int m2 = 0; m2 < 4; ++m2) {
                acc[m2] = MFMA16x16x32(a1f[(hh * 4 + m2) * 2],     blo, fzero);
                acc[m2] = MFMA16x16x32(a1f[(hh * 4 + m2) * 2 + 1], bhi, acc[m2]);
            }
            #pragma unroll
            for (int kb2 = 0; kb2 < 2; ++kb2) {
                u32x4 bv;
                bv[0] = pack2(rna(acc[2 * kb2][1]),     rna(acc[2 * kb2][0]));
                bv[1] = pack2(rna(acc[2 * kb2][3]),     rna(acc[2 * kb2][2]));
                bv[2] = pack2(rna(acc[2 * kb2 + 1][1]), rna(acc[2 * kb2 + 1][0]));
                bv[3] = pack2(rna(acc[2 * kb2 + 1][3]), rna(acc[2 * kb2 + 1][2]));
                u32x4 ba;
                #pragma unroll
                for (int j = 0; j < 4; ++j) ba[j] = bv[j] & 0x7FFF7FFFu;   // packed bf16 |v|
                acc2 = MFMA16x16x32(a2p[hh * 2 + kb2], bv, acc2);
                acc2 = MFMA16x16x32(a2n[hh * 2 + kb2], ba, acc2);
            }
        }

        const float sc = __shfl(scale_reg, pt * 16 + p16, 64);
        const size_t pixbase = (size_t)b * CHN * H * W + (size_t)h * W + p;
        #pragma unroll
        for (int r = 0; r < 4; ++r) {
            int o = g4 * 4 + r;
            if (o < OUTC) {
                // x center (bf16-rounded) is already in blo: slot 2*o -> element 2r
                float xhi = bits2f((unsigned short)blo[2 * r]);
                out[pixbase + (size_t)o * H * W] = fmaf(acc2[r], sc, xhi);
            }
        }
    }
}

extern "C" void kernel_launch(void* const* d_in, const int* in_sizes, int n_in,
                              void* d_out, int out_size, void* d_ws, size_t ws_size,
                              hipStream_t stream) {
    const float* x   = (const float*)d_in[0];
    const float* rnd = (const float*)d_in[1];
    const float* w1w = (const float*)d_in[2];
    const float* w1b = (const float*)d_in[3];
    const float* w2w = (const float*)d_in[4];
    float* out = (float*)d_out;
    unsigned short* ws = (unsigned short*)d_ws;

    prep_weights<<<dim3(1), dim3(256), 0, stream>>>(w1w, w1b, w2w, ws);
    nca_main<<<dim3(16 * 256), dim3(256), 0, stream>>>(x, rnd, ws, out);
}

// Round 14
// 51.990 us; speedup vs baseline: 1.1481x; 1.0070x over previous
//
#include <hip/hip_runtime.h>
#include <hip/hip_bf16.h>
#include <math.h>

#define CHN  12
#define H    256
#define W    256
#define HID  128
#define OUTC 9
#define PSTR 56   // perc row stride in shorts: 48 data + 8 const-pad (112 B -> 7-coprime slot rotation)

typedef __attribute__((ext_vector_type(4))) float    f32x4;
typedef __attribute__((ext_vector_type(8))) short    s16x8;
typedef __attribute__((ext_vector_type(4))) unsigned u32x4;
typedef __attribute__((ext_vector_type(8))) __bf16   bf16x8;

#define MFMA16x16x32(a, b, c) \
    __builtin_amdgcn_mfma_f32_16x16x32_bf16(__builtin_bit_cast(bf16x8, (a)), \
                                            __builtin_bit_cast(bf16x8, (b)), (c), 0, 0, 0)

static __device__ __forceinline__ unsigned short bfbits(float f) {
    __hip_bfloat16 h = __float2bfloat16(f);   // RNE (prep kernel only)
    return __builtin_bit_cast(unsigned short, h);
}
static __device__ __forceinline__ float bits2f(unsigned short u) {
    __hip_bfloat16 h = __builtin_bit_cast(__hip_bfloat16, u);
    return __bfloat162float(h);
}
// round-to-nearest-away bf16 in the bit domain: high 16 bits of (u + 0x8000)
static __device__ __forceinline__ unsigned rna(float f) {
    return __builtin_bit_cast(unsigned, f) + 0x8000u;
}
// pack two rna()'d words into bf16x2 (even -> low half, odd -> high half): 1 v_perm_b32
static __device__ __forceinline__ unsigned pack2(unsigned uodd, unsigned ueven) {
    return __builtin_amdgcn_perm(uodd, ueven, 0x07060302u);
}
static __device__ __forceinline__ float fast_sqrtf(float x) {
    float r;
    asm("v_sqrt_f32 %0, %1" : "=v"(r) : "v"(x));
    return r;
}

// ---------------- prologue: bake weight fragments into d_ws ----------------
// hid-row PERMUTATION (makes GEMM1 C-layout == GEMM2 B-layout per lane, no shuffle):
//   GEMM1 row-slot (m = hh*4+m2, rho = A-row 0..15)  -> physical hid = hh*64 + (rho>>2)*16 + m2*4 + (rho&3)
//   GEMM2 k-slot  (kb = hh*2+kb2, g4, j)             -> physical hid = hh*64 + g4*16 + kb2*8 + j
// ws layout:
//   [0)      a1  : ushort [16][64][8]  (mf = m*2+f; f=0 -> k 0..31, f=1 -> k 32..63)
//            k slots: 0..35 = w1 cols, 36..47 = w1 col 2(s-36)+1 (lap residual-lo
//            partner), 48 = w1b (pairs with constant 1.0 in perc pad), 49..63 = 0
//   [16384)  a2p : ushort [4][64][8]   bf16(0.505*w2)  -- pairs with v
//   [20480)  a2n : ushort [4][64][8]   bf16(0.495*w2)  -- pairs with |v|
//            (leaky(v) = 0.505 v + 0.495 |v|; v>0 -> v, v<0 -> 0.01 v)
__global__ void prep_weights(const float* __restrict__ w1w, const float* __restrict__ w1b,
                             const float* __restrict__ w2w, unsigned short* __restrict__ wsbuf)
{
    const int t = threadIdx.x;      // 256 threads, one block
    const int l = t & 63;
    const int grp = t >> 6;
    const int row = l & 15;         // rho (a1) / output channel (a2)
    const int g4 = l >> 4;
    unsigned short* wsa1  = wsbuf;
    unsigned short* wsa2p = wsbuf + 16 * 64 * 8;
    unsigned short* wsa2n = wsa2p + 4 * 64 * 8;

    for (int mf = grp; mf < 16; mf += 4) {
        int m = mf >> 1, f = mf & 1;
        int hh = m >> 2, m2 = m & 3;
        int hid = hh * 64 + (row >> 2) * 16 + m2 * 4 + (row & 3);   // permuted physical hid
        for (int j = 0; j < 8; ++j) {
            int s = f * 32 + g4 * 8 + j;
            unsigned short v = 0;
            if (s < 36)       v = bfbits(w1w[hid * 36 + s]);
            else if (s < 48)  v = bfbits(w1w[hid * 36 + 2 * (s - 36) + 1]);  // lap residual partner
            else if (s == 48) v = bfbits(w1b[hid]);                          // bias slot
            wsa1[(mf * 64 + l) * 8 + j] = v;
        }
    }
    {
        int kb = grp;
        int hh = kb >> 1, kb2 = kb & 1;
        for (int j = 0; j < 8; ++j) {
            int hid = hh * 64 + g4 * 16 + kb2 * 8 + j;              // same permutation
            float wv = (row < OUTC) ? w2w[row * HID + hid] : 0.f;
            wsa2p[(kb * 64 + l) * 8 + j] = bfbits(0.505f * wv);
            wsa2n[(kb * 64 + l) * 8 + j] = bfbits(0.495f * wv);
        }
    }
}

// ---------------- main fused kernel: one block per (batch,row) ----------------
__global__ __launch_bounds__(256, 3) void nca_main(
    const float* __restrict__ x, const float* __restrict__ rnd,
    const unsigned short* __restrict__ wsbuf, float* __restrict__ out)
{
    union SMem {
        struct { float2 csdd[CHN][W]; float prrow[W]; } s;  // live A..B only
        unsigned short perc[W][PSTR];                       // live C..E (28,672 B)
    };
    __shared__ SMem sm;   // total LDS = 28,672 B

    const int t = threadIdx.x;
    // XCD-aware bijective swizzle: XCD k gets contiguous orig ids -> halo reuse in its L2
    const int orig = ((blockIdx.x & 7) << 9) | (blockIdx.x >> 3);
    const int h = orig & (H - 1);
    const int b = orig >> 8;
    const int hm = (h + H - 1) & (H - 1);
    const int hp = (h + 1) & (H - 1);
    const float* xb = x + (size_t)b * CHN * H * W;

    // ---- phase A: vertical separable pass (registers), write col sums/diffs ----
    float xc[CHN], csr[CHN], ddr[CHN];
    const float maskraw = rnd[((size_t)b * H + h) * W + t];   // issue early
    #pragma unroll
    for (int c = 0; c < CHN; ++c) {
        const float* xp = xb + (size_t)c * H * W;
        float v0 = xp[hm * W + t];
        float v1 = xp[h  * W + t];
        float v2 = xp[hp * W + t];
        xc[c] = v1;
        float cs = fmaf(2.f, v1, v0) + v2;
        float dd = v2 - v0;
        csr[c] = cs; ddr[c] = dd;
        sm.s.csdd[c][t] = make_float2(cs, dd);
        if (c == 3) {   // pool col-max, CLAMPED h-edges
            float cm = v1;
            if (h > 0)     cm = fmaxf(cm, v0);
            if (h < H - 1) cm = fmaxf(cm, v2);
            sm.s.prrow[t] = cm;
        }
    }
    __syncthreads();

    // ---- phase B: horizontal pass -> perc[36], pool/life/mask ----
    const int wm = (t + W - 1) & (W - 1);
    const int wp = (t + 1) & (W - 1);
    float perc[36];
    #pragma unroll
    for (int c = 0; c < CHN; ++c) {
        float2 vm = sm.s.csdd[c][wm];
        float2 vp = sm.s.csdd[c][wp];
        float gx  = vp.x - vm.x;                            // SOBEL_X
        float gy  = fmaf(2.f, ddr[c], vm.y) + vp.y;         // SOBEL_X^T
        float lap = fmaf(2.f, csr[c], vm.x + vp.x) - 16.f * xc[c];
        perc[2 * c]     = xc[c];
        perc[2 * c + 1] = lap;
        perc[24 + c]    = fast_sqrtf(fmaf(gx, gx, gy * gy) + 1e-8f);
    }
    float scale_reg;
    {
        float pool = sm.s.prrow[t];
        if (t > 0)     pool = fmaxf(pool, sm.s.prrow[wm]);   // clamped w-edges
        if (t < W - 1) pool = fmaxf(pool, sm.s.prrow[wp]);
        scale_reg = (pool > 0.1f && maskraw >= 0.5f) ? 1.f : 0.f;  // floor(r+0.5) == (r>=0.5)
    }
    // ---- gene channels passthrough: store EARLY, frees regs through D/E ----
    {
        size_t gidx = ((size_t)b * CHN + 9) * H * W + (size_t)h * W + t;
        out[gidx]                     = xc[9];
        out[gidx + (size_t)H * W]     = xc[10];
        out[gidx + 2 * (size_t)H * W] = xc[11];
    }
    __syncthreads();   // everyone done reading sm.s before aliasing it with perc

    // ---- phase D (HOISTED): issue weight-fragment loads BEFORE phase C so their
    // L2 latency hides under C's VALU work; E consumes them with vmcnt in flight.
    const int l = t & 63;
    const int wv = t >> 6;
    const int p16 = l & 15;
    const int g4 = l >> 4;
    const s16x8* A1  = (const s16x8*)wsbuf;   // [16][64]
    const s16x8* A2P = A1 + 16 * 64;
    const s16x8* A2N = A2P + 4 * 64;

    s16x8 a1f[16];
    #pragma unroll
    for (int mf = 0; mf < 16; ++mf) a1f[mf] = A1[mf * 64 + l];
    s16x8 a2p[4], a2n[4];
    #pragma unroll
    for (int kb = 0; kb < 4; ++kb) { a2p[kb] = A2P[kb * 64 + l]; a2n[kb] = A2N[kb * 64 + l]; }

    // ---- phase C: bit-domain bf16 pack (RNA + v_perm), 6 data + 1 const granule ----
    {
        unsigned u[48];
        #pragma unroll
        for (int s = 0; s < 36; ++s) u[s] = rna(perc[s]);
        #pragma unroll
        for (int k = 0; k < 12; ++k) {
            float hif = __builtin_bit_cast(float, u[2 * k + 1] & 0xFFFF0000u);
            u[36 + k] = rna(perc[2 * k + 1] - hif);
        }
        unsigned short* prow = &sm.perc[t][0];
        #pragma unroll
        for (int g = 0; g < 6; ++g) {
            u32x4 v;
            #pragma unroll
            for (int j = 0; j < 4; ++j)
                v[j] = pack2(u[8 * g + 2 * j + 1], u[8 * g + 2 * j]);
            *(u32x4*)&prow[g * 8] = v;
        }
        // const pad granule, slots 48..55: {1.0(bias partner), 0 x 7}
        u32x4 vpad;
        vpad[0] = 0x3F80u; vpad[1] = 0u; vpad[2] = 0u; vpad[3] = 0u;
        *(u32x4*)&prow[48] = vpad;
    }
    // perc rows for this wave's 64 pixels were written by this same wave -> no barrier.

    const f32x4 fzero = {0.f, 0.f, 0.f, 0.f};

    // ---- phase E: per-16-pixel tile: GEMM1 -> lane-local repack -> GEMM2 -> store ----
    // acc2 split into two independent 4-deep chains (p and n), summed at the end.
    #pragma unroll
    for (int pt = 0; pt < 4; ++pt) {
        const int p = wv * 64 + pt * 16 + p16;
        const unsigned short* prow = &sm.perc[p][0];
        s16x8 blo = *(const s16x8*)&prow[g4 * 8];               // k 0..31
        s16x8 bhi;
        #pragma unroll
        for (int j = 0; j < 8; ++j) bhi[j] = 0;                 // k 48..63 zeros (g4==3)
        if (g4 < 3) bhi = *(const s16x8*)&prow[(4 + g4) * 8];   // k 32..55 incl. const pad

        f32x4 acc2p = fzero, acc2n = fzero;

        #pragma unroll
        for (int hh = 0; hh < 2; ++hh) {
            f32x4 acc[4];
            #pragma unroll
            for (int m2 = 0; m2 < 4; ++m2) {
                acc[m2] = MFMA16x16x32(a1f[(hh * 4 + m2) * 2],     blo, fzero);
                acc[m2] = MFMA16x16x32(a1f[(hh * 4 + m2) * 2 + 1], bhi, acc[m2]);
            }
            #pragma unroll
            for (int kb2 = 0; kb2 < 2; ++kb2) {
                u32x4 bv;
                bv[0] = pack2(rna(acc[2 * kb2][1]),     rna(acc[2 * kb2][0]));
                bv[1] = pack2(rna(acc[2 * kb2][3]),     rna(acc[2 * kb2][2]));
                bv[2] = pack2(rna(acc[2 * kb2 + 1][1]), rna(acc[2 * kb2 + 1][0]));
                bv[3] = pack2(rna(acc[2 * kb2 + 1][3]), rna(acc[2 * kb2 + 1][2]));
                u32x4 ba;
                #pragma unroll
                for (int j = 0; j < 4; ++j) ba[j] = bv[j] & 0x7FFF7FFFu;   // packed bf16 |v|
                acc2p = MFMA16x16x32(a2p[hh * 2 + kb2], bv, acc2p);
                acc2n = MFMA16x16x32(a2n[hh * 2 + kb2], ba, acc2n);
            }
        }

        const float sc = __shfl(scale_reg, pt * 16 + p16, 64);
        const size_t pixbase = (size_t)b * CHN * H * W + (size_t)h * W + p;
        #pragma unroll
        for (int r = 0; r < 4; ++r) {
            int o = g4 * 4 + r;
            if (o < OUTC) {
                // x center (bf16-rounded) is already in blo: slot 2*o -> element 2r
                float xhi = bits2f((unsigned short)blo[2 * r]);
                out[pixbase + (size_t)o * H * W] = fmaf(acc2p[r] + acc2n[r], sc, xhi);
            }
        }
    }
}

extern "C" void kernel_launch(void* const* d_in, const int* in_sizes, int n_in,
                              void* d_out, int out_size, void* d_ws, size_t ws_size,
                              hipStream_t stream) {
    const float* x   = (const float*)d_in[0];
    const float* rnd = (const float*)d_in[1];
    const float* w1w = (const float*)d_in[2];
    const float* w1b = (const float*)d_in[3];
    const float* w2w = (const float*)d_in[4];
    float* out = (float*)d_out;
    unsigned short* ws = (unsigned short*)d_ws;

    prep_weights<<<dim3(1), dim3(256), 0, stream>>>(w1w, w1b, w2w, ws);
    nca_main<<<dim3(16 * 256), dim3(256), 0, stream>>>(x, rnd, ws, out);
}

// Round 15
// 51.678 us; speedup vs baseline: 1.1550x; 1.0060x over previous
//
#include <hip/hip_runtime.h>
#include <hip/hip_bf16.h>
#include <math.h>

#define CHN  12
#define H    256
#define W    256
#define HID  128
#define OUTC 9
#define PSTR 56   // perc row stride in shorts: 48 data + 8 const-pad (112 B -> 7-coprime slot rotation)

typedef __attribute__((ext_vector_type(4))) float    f32x4;
typedef __attribute__((ext_vector_type(8))) short    s16x8;
typedef __attribute__((ext_vector_type(4))) unsigned u32x4;
typedef __attribute__((ext_vector_type(8))) __bf16   bf16x8;

#define MFMA16x16x32(a, b, c) \
    __builtin_amdgcn_mfma_f32_16x16x32_bf16(__builtin_bit_cast(bf16x8, (a)), \
                                            __builtin_bit_cast(bf16x8, (b)), (c), 0, 0, 0)

static __device__ __forceinline__ unsigned short bfbits(float f) {
    __hip_bfloat16 h = __float2bfloat16(f);   // RNE (prep kernel only)
    return __builtin_bit_cast(unsigned short, h);
}
static __device__ __forceinline__ float bits2f(unsigned short u) {
    __hip_bfloat16 h = __builtin_bit_cast(__hip_bfloat16, u);
    return __bfloat162float(h);
}
// round-to-nearest-away bf16 in the bit domain: high 16 bits of (u + 0x8000)
static __device__ __forceinline__ unsigned rna(float f) {
    return __builtin_bit_cast(unsigned, f) + 0x8000u;
}
// pack two rna()'d words into bf16x2 (even -> low half, odd -> high half): 1 v_perm_b32
static __device__ __forceinline__ unsigned pack2(unsigned uodd, unsigned ueven) {
    return __builtin_amdgcn_perm(uodd, ueven, 0x07060302u);
}
static __device__ __forceinline__ float fast_sqrtf(float x) {
    float r;
    asm("v_sqrt_f32 %0, %1" : "=v"(r) : "v"(x));
    return r;
}

// ---------------- prologue: bake weight fragments into d_ws ----------------
// hid-row PERMUTATION (makes GEMM1 C-layout == GEMM2 B-layout per lane, no shuffle):
//   GEMM1 row-slot (m = hh*4+m2, rho = A-row 0..15)  -> physical hid = hh*64 + (rho>>2)*16 + m2*4 + (rho&3)
//   GEMM2 k-slot  (kb = hh*2+kb2, g4, j)             -> physical hid = hh*64 + g4*16 + kb2*8 + j
// ws layout:
//   [0)      a1  : ushort [16][64][8]  (mf = m*2+f; f=0 -> k 0..31, f=1 -> k 32..63)
//            k slots: 0..35 = w1 cols, 36..47 = w1 col 2(s-36)+1 (lap residual-lo
//            partner), 48 = w1b (pairs with constant 1.0 in perc pad), 49..63 = 0
//   [16384)  a2p : ushort [4][64][8]   bf16(0.505*w2)  -- pairs with v
//   [20480)  a2n : ushort [4][64][8]   bf16(0.495*w2)  -- pairs with |v|
//            (leaky(v) = 0.505 v + 0.495 |v|; v>0 -> v, v<0 -> 0.01 v)
__global__ void prep_weights(const float* __restrict__ w1w, const float* __restrict__ w1b,
                             const float* __restrict__ w2w, unsigned short* __restrict__ wsbuf)
{
    const int t = threadIdx.x;      // 256 threads, one block
    const int l = t & 63;
    const int grp = t >> 6;
    const int row = l & 15;         // rho (a1) / output channel (a2)
    const int g4 = l >> 4;
    unsigned short* wsa1  = wsbuf;
    unsigned short* wsa2p = wsbuf + 16 * 64 * 8;
    unsigned short* wsa2n = wsa2p + 4 * 64 * 8;

    for (int mf = grp; mf < 16; mf += 4) {
        int m = mf >> 1, f = mf & 1;
        int hh = m >> 2, m2 = m & 3;
        int hid = hh * 64 + (row >> 2) * 16 + m2 * 4 + (row & 3);   // permuted physical hid
        for (int j = 0; j < 8; ++j) {
            int s = f * 32 + g4 * 8 + j;
            unsigned short v = 0;
            if (s < 36)       v = bfbits(w1w[hid * 36 + s]);
            else if (s < 48)  v = bfbits(w1w[hid * 36 + 2 * (s - 36) + 1]);  // lap residual partner
            else if (s == 48) v = bfbits(w1b[hid]);                          // bias slot
            wsa1[(mf * 64 + l) * 8 + j] = v;
        }
    }
    {
        int kb = grp;
        int hh = kb >> 1, kb2 = kb & 1;
        for (int j = 0; j < 8; ++j) {
            int hid = hh * 64 + g4 * 16 + kb2 * 8 + j;              // same permutation
            float wv = (row < OUTC) ? w2w[row * HID + hid] : 0.f;
            wsa2p[(kb * 64 + l) * 8 + j] = bfbits(0.505f * wv);
            wsa2n[(kb * 64 + l) * 8 + j] = bfbits(0.495f * wv);
        }
    }
}

// ---------------- main fused kernel: one block per (batch,row) ----------------
// __launch_bounds__(256,2): matches the TRUE residency (weights in AGPR push
// per-wave regs past 170 anyway) -> allocator gets ~256 regs, no reloads, and
// phase E is restructured as 4 fully independent tile chains for per-wave ILP.
__global__ __launch_bounds__(256, 2) void nca_main(
    const float* __restrict__ x, const float* __restrict__ rnd,
    const unsigned short* __restrict__ wsbuf, float* __restrict__ out)
{
    union SMem {
        struct { float2 csdd[CHN][W]; float prrow[W]; } s;  // live A..B only
        unsigned short perc[W][PSTR];                       // live C..E (28,672 B)
    };
    __shared__ SMem sm;   // total LDS = 28,672 B

    const int t = threadIdx.x;
    // XCD-aware bijective swizzle: XCD k gets contiguous orig ids -> halo reuse in its L2
    const int orig = ((blockIdx.x & 7) << 9) | (blockIdx.x >> 3);
    const int h = orig & (H - 1);
    const int b = orig >> 8;
    const int hm = (h + H - 1) & (H - 1);
    const int hp = (h + 1) & (H - 1);
    const float* xb = x + (size_t)b * CHN * H * W;

    // ---- phase A: vertical separable pass (registers), write col sums/diffs ----
    float xc[CHN], csr[CHN], ddr[CHN];
    const float maskraw = rnd[((size_t)b * H + h) * W + t];   // issue early
    #pragma unroll
    for (int c = 0; c < CHN; ++c) {
        const float* xp = xb + (size_t)c * H * W;
        float v0 = xp[hm * W + t];
        float v1 = xp[h  * W + t];
        float v2 = xp[hp * W + t];
        xc[c] = v1;
        float cs = fmaf(2.f, v1, v0) + v2;
        float dd = v2 - v0;
        csr[c] = cs; ddr[c] = dd;
        sm.s.csdd[c][t] = make_float2(cs, dd);
        if (c == 3) {   // pool col-max, CLAMPED h-edges
            float cm = v1;
            if (h > 0)     cm = fmaxf(cm, v0);
            if (h < H - 1) cm = fmaxf(cm, v2);
            sm.s.prrow[t] = cm;
        }
    }
    __syncthreads();

    // ---- phase B: horizontal pass -> perc[36], pool/life/mask ----
    const int wm = (t + W - 1) & (W - 1);
    const int wp = (t + 1) & (W - 1);
    float perc[36];
    #pragma unroll
    for (int c = 0; c < CHN; ++c) {
        float2 vm = sm.s.csdd[c][wm];
        float2 vp = sm.s.csdd[c][wp];
        float gx  = vp.x - vm.x;                            // SOBEL_X
        float gy  = fmaf(2.f, ddr[c], vm.y) + vp.y;         // SOBEL_X^T
        float lap = fmaf(2.f, csr[c], vm.x + vp.x) - 16.f * xc[c];
        perc[2 * c]     = xc[c];
        perc[2 * c + 1] = lap;
        perc[24 + c]    = fast_sqrtf(fmaf(gx, gx, gy * gy) + 1e-8f);
    }
    float scale_reg;
    {
        float pool = sm.s.prrow[t];
        if (t > 0)     pool = fmaxf(pool, sm.s.prrow[wm]);   // clamped w-edges
        if (t < W - 1) pool = fmaxf(pool, sm.s.prrow[wp]);
        scale_reg = (pool > 0.1f && maskraw >= 0.5f) ? 1.f : 0.f;  // floor(r+0.5) == (r>=0.5)
    }
    // ---- gene channels passthrough: store EARLY, frees regs through D/E ----
    {
        size_t gidx = ((size_t)b * CHN + 9) * H * W + (size_t)h * W + t;
        out[gidx]                     = xc[9];
        out[gidx + (size_t)H * W]     = xc[10];
        out[gidx + 2 * (size_t)H * W] = xc[11];
    }
    __syncthreads();   // everyone done reading sm.s before aliasing it with perc

    // ---- phase D (hoisted): weight-fragment loads issue before phase C ----
    const int l = t & 63;
    const int wv = t >> 6;
    const int p16 = l & 15;
    const int g4 = l >> 4;
    const s16x8* A1  = (const s16x8*)wsbuf;   // [16][64]
    const s16x8* A2P = A1 + 16 * 64;
    const s16x8* A2N = A2P + 4 * 64;

    s16x8 a1f[16];
    #pragma unroll
    for (int mf = 0; mf < 16; ++mf) a1f[mf] = A1[mf * 64 + l];
    s16x8 a2p[4], a2n[4];
    #pragma unroll
    for (int kb = 0; kb < 4; ++kb) { a2p[kb] = A2P[kb * 64 + l]; a2n[kb] = A2N[kb * 64 + l]; }

    // ---- phase C: bit-domain bf16 pack (RNA + v_perm), 6 data + 1 const granule ----
    {
        unsigned u[48];
        #pragma unroll
        for (int s = 0; s < 36; ++s) u[s] = rna(perc[s]);
        #pragma unroll
        for (int k = 0; k < 12; ++k) {
            float hif = __builtin_bit_cast(float, u[2 * k + 1] & 0xFFFF0000u);
            u[36 + k] = rna(perc[2 * k + 1] - hif);
        }
        unsigned short* prow = &sm.perc[t][0];
        #pragma unroll
        for (int g = 0; g < 6; ++g) {
            u32x4 v;
            #pragma unroll
            for (int j = 0; j < 4; ++j)
                v[j] = pack2(u[8 * g + 2 * j + 1], u[8 * g + 2 * j]);
            *(u32x4*)&prow[g * 8] = v;
        }
        // const pad granule, slots 48..55: {1.0(bias partner), 0 x 7}
        u32x4 vpad;
        vpad[0] = 0x3F80u; vpad[1] = 0u; vpad[2] = 0u; vpad[3] = 0u;
        *(u32x4*)&prow[48] = vpad;
    }
    // perc rows for this wave's 64 pixels were written by this same wave -> no barrier.

    const f32x4 fzero = {0.f, 0.f, 0.f, 0.f};

    // ---- phase E: preload ALL 4 tiles' B-fragments, then 4 independent chains ----
    s16x8 blo4[4], bhi4[4];
    #pragma unroll
    for (int pt = 0; pt < 4; ++pt) {
        const unsigned short* prow = &sm.perc[wv * 64 + pt * 16 + p16][0];
        blo4[pt] = *(const s16x8*)&prow[g4 * 8];                  // k 0..31
        if (g4 < 3) {
            bhi4[pt] = *(const s16x8*)&prow[(4 + g4) * 8];        // k 32..55 incl. const pad
        } else {
            #pragma unroll
            for (int j = 0; j < 8; ++j) bhi4[pt][j] = 0;          // k 48..63 zeros
        }
    }

    #pragma unroll
    for (int pt = 0; pt < 4; ++pt) {
        f32x4 acc2p = fzero, acc2n = fzero;

        #pragma unroll
        for (int hh = 0; hh < 2; ++hh) {
            f32x4 acc[4];
            #pragma unroll
            for (int m2 = 0; m2 < 4; ++m2) {
                acc[m2] = MFMA16x16x32(a1f[(hh * 4 + m2) * 2],     blo4[pt], fzero);
                acc[m2] = MFMA16x16x32(a1f[(hh * 4 + m2) * 2 + 1], bhi4[pt], acc[m2]);
            }
            // lane-local repack (hid permutation baked into weights): RNA + v_perm
            #pragma unroll
            for (int kb2 = 0; kb2 < 2; ++kb2) {
                u32x4 bv;
                bv[0] = pack2(rna(acc[2 * kb2][1]),     rna(acc[2 * kb2][0]));
                bv[1] = pack2(rna(acc[2 * kb2][3]),     rna(acc[2 * kb2][2]));
                bv[2] = pack2(rna(acc[2 * kb2 + 1][1]), rna(acc[2 * kb2 + 1][0]));
                bv[3] = pack2(rna(acc[2 * kb2 + 1][3]), rna(acc[2 * kb2 + 1][2]));
                u32x4 ba;
                #pragma unroll
                for (int j = 0; j < 4; ++j) ba[j] = bv[j] & 0x7FFF7FFFu;   // packed bf16 |v|
                acc2p = MFMA16x16x32(a2p[hh * 2 + kb2], bv, acc2p);
                acc2n = MFMA16x16x32(a2n[hh * 2 + kb2], ba, acc2n);
            }
        }

        const int p = wv * 64 + pt * 16 + p16;
        const float sc = __shfl(scale_reg, pt * 16 + p16, 64);
        const size_t pixbase = (size_t)b * CHN * H * W + (size_t)h * W + p;
        #pragma unroll
        for (int r = 0; r < 4; ++r) {
            int o = g4 * 4 + r;
            if (o < OUTC) {
                // x center (bf16-rounded) is already in blo4: slot 2*o -> element 2r
                float xhi = bits2f((unsigned short)blo4[pt][2 * r]);
                out[pixbase + (size_t)o * H * W] = fmaf(acc2p[r] + acc2n[r], sc, xhi);
            }
        }
    }
}

extern "C" void kernel_launch(void* const* d_in, const int* in_sizes, int n_in,
                              void* d_out, int out_size, void* d_ws, size_t ws_size,
                              hipStream_t stream) {
    const float* x   = (const float*)d_in[0];
    const float* rnd = (const float*)d_in[1];
    const float* w1w = (const float*)d_in[2];
    const float* w1b = (const float*)d_in[3];
    const float* w2w = (const float*)d_in[4];
    float* out = (float*)d_out;
    unsigned short* ws = (unsigned short*)d_ws;

    prep_weights<<<dim3(1), dim3(256), 0, stream>>>(w1w, w1b, w2w, ws);
    nca_main<<<dim3(16 * 256), dim3(256), 0, stream>>>(x, rnd, ws, out);
}